// Round 2
// baseline (12529.302 us; speedup 1.0000x reference)
//
#include <hip/hip_runtime.h>

// ---------------------------------------------------------------------------
// Batched 12-qubit state-vector sim, one wave (64 lanes) per sample.
// State: 4096 complex amps = 64 complex per lane, all in VGPRs.
// Flat index y (12 bits) = (lane<<6) | reg.  Wire w <-> flat bit p = 11-w.
//   wires 0..5  -> lane bits 5..0  (cross-lane gates via ds_bpermute)
//   wires 6..11 -> reg  bits 5..0  (pure register gates)
// CNOT chain (ctrl=i,tgt=i+1) == new[d] = old[d ^ (d>>1)]:
//   new[l][r] = old[gray(l)][gray6(r) ^ 32*(l&1)]
// Last layer's CNOT is elided: folded into epilogue sign masks
// (bit_p(M^{-1}(e)) = parity of bits p..11 of e  =>  prefix-parity masks).
// Rot(phi,th,om) = [[(A,-B),(-C,-D)],[(C,-D),(A,B)]],
//   A=ca*ch B=sa*ch C=cb*sh D=sb*sh  (only 4 live coeff registers).
// __launch_bounds__(256,3): cap VGPR<=170 -> 3 waves/SIMD for latency hiding.
// ---------------------------------------------------------------------------

__device__ __forceinline__ float bperm(int addr4, float v) {
    return __int_as_float(__builtin_amdgcn_ds_bpermute(addr4, __float_as_int(v)));
}

__device__ __forceinline__ void rot_coeffs(float phi, float th, float om,
                                           float& A, float& B, float& C, float& D) {
    float ch, sh, ca, sa, cb, sb;
    __sincosf(0.5f*th,       &sh, &ch);
    __sincosf(0.5f*(phi+om), &sa, &ca);
    __sincosf(0.5f*(phi-om), &sb, &cb);
    A = ca*ch; B = sa*ch; C = cb*sh; D = sb*sh;
}

// Gate on a LANE bit. Element-based: out = cs*x + co*partner, coefficients
// pre-selected per lane. Software-pipelined bperm prefetch (chunk=4 -> max 16
// outstanding DS ops, 16 temp VGPRs).
__device__ __forceinline__ void lane_gate(float ar[64], float ai[64], int addr4,
                                          float csr, float csi, float cor, float coi) {
    constexpr int CH = 4;
    float tr[CH], ti[CH], pr[CH], pi[CH];
#pragma unroll
    for (int k = 0; k < CH; ++k) { tr[k] = bperm(addr4, ar[k]); ti[k] = bperm(addr4, ai[k]); }
#pragma unroll
    for (int base = 0; base < 64; base += CH) {
        if (base + CH < 64) {
#pragma unroll
            for (int k = 0; k < CH; ++k) {
                pr[k] = bperm(addr4, ar[base+CH+k]);
                pi[k] = bperm(addr4, ai[base+CH+k]);
            }
        }
#pragma unroll
        for (int k = 0; k < CH; ++k) {
            const int r = base + k;
            const float xr = ar[r], xi = ai[r];
            ar[r] = csr*xr - csi*xi + cor*tr[k] - coi*ti[k];
            ai[r] = csr*xi + csi*xr + cor*ti[k] + coi*tr[k];
        }
#pragma unroll
        for (int k = 0; k < CH; ++k) { tr[k] = pr[k]; ti[k] = pi[k]; }
    }
}

// Gate on a REGISTER bit P, Rot-structured (A,B,C,D).
template<int P>
__device__ __forceinline__ void reg_gate(float ar[64], float ai[64],
                                         float A, float B, float C, float D) {
#pragma unroll
    for (int i0 = 0; i0 < 64; ++i0) {
        if (i0 & (1 << P)) continue;          // compile-time filtered
        const int i1 = i0 | (1 << P);
        const float a0r = ar[i0], a0i = ai[i0], a1r = ar[i1], a1i = ai[i1];
        ar[i0] = A*a0r + B*a0i - C*a1r + D*a1i;
        ai[i0] = A*a0i - B*a0r - C*a1i - D*a1r;
        ar[i1] = C*a0r + D*a0i + A*a1r - B*a1i;
        ai[i1] = C*a0i - D*a0r + A*a1i + B*a1r;
    }
}

// CNOT chain: bperm first (fills DS pipe), then fused relabel+half-swap select.
__device__ __forceinline__ void cnot_perm(float ar[64], float ai[64], int lane) {
    const int ga4 = (lane ^ (lane >> 1)) << 2;
    float br[64], bi[64];
#pragma unroll
    for (int r = 0; r < 64; ++r) { br[r] = bperm(ga4, ar[r]); bi[r] = bperm(ga4, ai[r]); }
    const bool odd = lane & 1;
#pragma unroll
    for (int r = 0; r < 64; ++r) {
        const int s = r ^ (r >> 1);
        ar[r] = odd ? br[s ^ 32] : br[s];
        ai[r] = odd ? bi[s ^ 32] : bi[s];
    }
}

__global__ __launch_bounds__(256, 3)
void qsim_kernel(const float* __restrict__ sb,   // (B,8) state_batch
                 const float* __restrict__ wts,  // (8,12,3) weights
                 const float* __restrict__ hw,   // (1,12) head_w
                 const float* __restrict__ hb,   // (1,) head_b
                 float* __restrict__ out,        // (B,)
                 int B) {
    const int lane   = threadIdx.x & 63;
    const int sample = blockIdx.x * 4 + (threadIdx.x >> 6);
    if (sample >= B) return;

    // ---- init directly to post-encoding state RX(x0)@w0, RY(x1)@w1 on |0..0>:
    // nonzero only at reg 0, lanes {0,16,32,48}.
    float c0, s0, c1, s1;
    __sincosf(0.5f * sb[sample*8 + 0], &s0, &c0);
    __sincosf(0.5f * sb[sample*8 + 1], &s1, &c1);
    float ar[64], ai[64];
#pragma unroll
    for (int r = 0; r < 64; ++r) { ar[r] = 0.f; ai[r] = 0.f; }
    {
        float a0 = 0.f, b0 = 0.f;
        if (lane == 0)  a0 =  c0*c1;
        if (lane == 16) a0 =  c0*s1;
        if (lane == 32) b0 = -s0*c1;
        if (lane == 48) b0 = -s0*s1;
        ar[0] = a0; ai[0] = b0;
    }

#pragma unroll 1
    for (int l = 0; l < 8; ++l) {
        const float* lw = wts + l*36;
        // wires 0..5 -> lane bits 5..0
#pragma unroll 1
        for (int w = 0; w < 6; ++w) {
            float A, Bc, C, D;
            rot_coeffs(lw[w*3+0], lw[w*3+1], lw[w*3+2], A, Bc, C, D);
            const int pb = 5 - w;
            const bool b = (lane >> pb) & 1;
            lane_gate(ar, ai, (lane ^ (1 << pb)) << 2,
                      A, b ? Bc : -Bc, b ? C : -C, -D);
        }
        // wires 6..11 -> reg bits 5..0
        { float A,Bc,C,D; rot_coeffs(lw[18],lw[19],lw[20],A,Bc,C,D); reg_gate<5>(ar,ai,A,Bc,C,D); }
        { float A,Bc,C,D; rot_coeffs(lw[21],lw[22],lw[23],A,Bc,C,D); reg_gate<4>(ar,ai,A,Bc,C,D); }
        { float A,Bc,C,D; rot_coeffs(lw[24],lw[25],lw[26],A,Bc,C,D); reg_gate<3>(ar,ai,A,Bc,C,D); }
        { float A,Bc,C,D; rot_coeffs(lw[27],lw[28],lw[29],A,Bc,C,D); reg_gate<2>(ar,ai,A,Bc,C,D); }
        { float A,Bc,C,D; rot_coeffs(lw[30],lw[31],lw[32],A,Bc,C,D); reg_gate<1>(ar,ai,A,Bc,C,D); }
        { float A,Bc,C,D; rot_coeffs(lw[33],lw[34],lw[35],A,Bc,C,D); reg_gate<0>(ar,ai,A,Bc,C,D); }
        if (l < 7) cnot_perm(ar, ai, lane);
    }

    // ---- epilogue (pre-last-CNOT state, prefix-parity sign masks):
    // wire w in 0..5 : sign = parity(lane >> (5-w))
    // wire w in 6..11: sign = parity(lane) * parity(r >> (11-w))
    float T = 0.f, S0=0.f,S1=0.f,S2=0.f,S3=0.f,S4=0.f,S5=0.f;
#pragma unroll
    for (int r = 0; r < 64; ++r) {
        const float p = ar[r]*ar[r] + ai[r]*ai[r];
        T  += p;
        S0 += (__builtin_popcount(r >> 0) & 1) ? -p : p;
        S1 += (__builtin_popcount(r >> 1) & 1) ? -p : p;
        S2 += (__builtin_popcount(r >> 2) & 1) ? -p : p;
        S3 += (__builtin_popcount(r >> 3) & 1) ? -p : p;
        S4 += (__builtin_popcount(r >> 4) & 1) ? -p : p;
        S5 += (__builtin_popcount(r >> 5) & 1) ? -p : p;
    }
    float WL = 0.f;
#pragma unroll
    for (int w = 0; w < 6; ++w) {
        const float h = hw[w];
        WL += (__popc(lane >> (5 - w)) & 1) ? -h : h;
    }
    float SR = hw[6]*S5 + hw[7]*S4 + hw[8]*S3
             + hw[9]*S2 + hw[10]*S1 + hw[11]*S0;
    float u = T*WL + ((__popc(lane) & 1) ? -SR : SR);
#pragma unroll
    for (int off = 1; off < 64; off <<= 1)
        u += bperm((lane ^ off) << 2, u);
    if (lane == 0) out[sample] = u + hb[0];
}

extern "C" void kernel_launch(void* const* d_in, const int* in_sizes, int n_in,
                              void* d_out, int out_size, void* d_ws, size_t ws_size,
                              hipStream_t stream) {
    const float* sb  = (const float*)d_in[0];
    const float* wts = (const float*)d_in[1];
    const float* hw  = (const float*)d_in[2];
    const float* hb  = (const float*)d_in[3];
    float* out = (float*)d_out;
    const int B = in_sizes[0] / 8;            // (B,8) state_batch
    const int blocks = (B + 3) / 4;           // 4 waves (samples) per 256-thread block
    qsim_kernel<<<blocks, 256, 0, stream>>>(sb, wts, hw, hb, out, B);
}

// Round 3
// 1057.881 us; speedup vs baseline: 11.8438x; 11.8438x over previous
//
#include <hip/hip_runtime.h>

// ---------------------------------------------------------------------------
// Batched 12-qubit state-vector sim, one wave (64 lanes) per sample.
// State: 4096 complex amps = 64 complex per lane, held as float2-packed
// register arrays ar2[32], ai2[32] (element r = 2k+h lives in half h of
// float2 k). All gate coefficients are uniform across elements, so packing
// element-pairs makes every gate update a v_pk_fma_f32 candidate (2 FMA/inst,
// CDNA double-rate fp32).
// Flat index y (12 bits) = (lane<<6) | reg.  Wire w <-> flat bit p = 11-w.
//   wires 0..5  -> lane bits 5..0  (cross-lane gates via ds_bpermute)
//   wires 6..11 -> reg  bits 5..0  (in-register gates)
// CNOT chain (ctrl=i,tgt=i+1) == new[d] = old[d ^ (d>>1)]:
//   new[l][r] = old[gray(l)][gray6(r) ^ 32*(l&1)]
// Last layer's CNOT is elided: folded into epilogue prefix-parity sign masks.
// Rot(phi,th,om) = [[(A,-B),(-C,-D)],[(C,-D),(A,B)]], A=ca*ch B=sa*ch
// C=cb*sh D=sb*sh.
// NO min-waves launch bound: round 2 showed capping VGPR below state size
// (128 regs) spills the whole state to scratch (FETCH 373KB -> 14.7GB,
// 8.4x slower). 2 waves/SIMD at ~196 VGPR is the design point.
// ---------------------------------------------------------------------------

__device__ __forceinline__ float bperm(int addr4, float v) {
    return __int_as_float(__builtin_amdgcn_ds_bpermute(addr4, __float_as_int(v)));
}

// float2 helpers written as componentwise fmaf so SLP forms <2 x float> fma
// -> v_pk_fma_f32. Scalar coefficient broadcasts; sign folds into fma neg mod.
__device__ __forceinline__ float2 fm(float s, float2 v, float2 acc) {
    return make_float2(__builtin_fmaf(s, v.x, acc.x), __builtin_fmaf(s, v.y, acc.y));
}
__device__ __forceinline__ float2 ml(float s, float2 v) {
    return make_float2(s * v.x, s * v.y);
}
__device__ __forceinline__ float2 pf(float2 c, float2 v, float2 acc) {
    return make_float2(__builtin_fmaf(c.x, v.x, acc.x), __builtin_fmaf(c.y, v.y, acc.y));
}
__device__ __forceinline__ float2 pm(float2 c, float2 v) {
    return make_float2(c.x * v.x, c.y * v.y);
}
// compile-time scalar element access (idx must be a constant after unroll)
__device__ __forceinline__ float getc(const float2 a[32], int idx) {
    return (idx & 1) ? a[idx >> 1].y : a[idx >> 1].x;
}

__device__ __forceinline__ void rot_coeffs(float phi, float th, float om,
                                           float& A, float& B, float& C, float& D) {
    float ch, sh, ca, sa, cb, sb;
    __sincosf(0.5f*th,       &sh, &ch);
    __sincosf(0.5f*(phi+om), &sa, &ca);
    __sincosf(0.5f*(phi-om), &sb, &cb);
    A = ca*ch; B = sa*ch; C = cb*sh; D = sb*sh;
}

// Gate on a LANE bit. out = cs*x + co*partner, per-lane scalar coefficients.
// Software-pipelined bperm prefetch, CH float2s per chunk (16 DS in flight).
__device__ __forceinline__ void lane_gate(float2 ar2[32], float2 ai2[32], int addr4,
                                          float csr, float csi, float cor, float coi) {
    constexpr int CH = 4;
    float2 tr[CH], ti[CH], pr[CH], pi[CH];
#pragma unroll
    for (int k = 0; k < CH; ++k) {
        tr[k] = make_float2(bperm(addr4, ar2[k].x), bperm(addr4, ar2[k].y));
        ti[k] = make_float2(bperm(addr4, ai2[k].x), bperm(addr4, ai2[k].y));
    }
#pragma unroll
    for (int base = 0; base < 32; base += CH) {
        if (base + CH < 32) {
#pragma unroll
            for (int k = 0; k < CH; ++k) {
                pr[k] = make_float2(bperm(addr4, ar2[base+CH+k].x), bperm(addr4, ar2[base+CH+k].y));
                pi[k] = make_float2(bperm(addr4, ai2[base+CH+k].x), bperm(addr4, ai2[base+CH+k].y));
            }
        }
#pragma unroll
        for (int k = 0; k < CH; ++k) {
            const int r = base + k;
            const float2 xr = ar2[r], xi = ai2[r];
            // ar = csr*xr - csi*xi + cor*tr - coi*ti
            ar2[r] = fm(-coi, ti[k], fm(cor, tr[k], fm(-csi, xi, ml(csr, xr))));
            // ai = csr*xi + csi*xr + cor*ti + coi*tr
            ai2[r] = fm( coi, tr[k], fm(cor, ti[k], fm( csi, xr, ml(csr, xi))));
        }
#pragma unroll
        for (int k = 0; k < CH; ++k) { tr[k] = pr[k]; ti[k] = pi[k]; }
    }
}

// Gate on reg bit P>=1 (float2-index bit P-1): pairs of whole float2s.
template<int P2>
__device__ __forceinline__ void reg_gate_hi(float2 ar2[32], float2 ai2[32],
                                            float A, float B, float C, float D) {
#pragma unroll
    for (int k0 = 0; k0 < 32; ++k0) {
        if (k0 & (1 << P2)) continue;          // compile-time filtered
        const int k1 = k0 | (1 << P2);
        const float2 a0r = ar2[k0], a0i = ai2[k0], a1r = ar2[k1], a1i = ai2[k1];
        ar2[k0] = fm( D, a1i, fm(-C, a1r, fm( B, a0i, ml(A, a0r))));
        ai2[k0] = fm(-D, a1r, fm(-C, a1i, fm(-B, a0r, ml(A, a0i))));
        ar2[k1] = fm(-B, a1i, fm( A, a1r, fm( D, a0i, ml(C, a0r))));
        ai2[k1] = fm( B, a1r, fm( A, a1i, fm(-D, a0r, ml(C, a0i))));
    }
}

// Gate on reg bit 0: pair lives inside one float2. Per-half coefficient
// pairs + half-broadcasts keep it packed.
__device__ __forceinline__ void reg_gate_lo(float2 ar2[32], float2 ai2[32],
                                            float A, float B, float C, float D) {
    const float2 cP  = make_float2( A,  C);
    const float2 cQ  = make_float2( B,  D);
    const float2 cR  = make_float2(-C,  A);
    const float2 cS  = make_float2( D, -B);
    const float2 cQn = make_float2(-B, -D);
    const float2 cSn = make_float2(-D,  B);
#pragma unroll
    for (int k = 0; k < 32; ++k) {
        const float2 arv = ar2[k], aiv = ai2[k];
        const float2 arx = make_float2(arv.x, arv.x), ary = make_float2(arv.y, arv.y);
        const float2 aix = make_float2(aiv.x, aiv.x), aiy = make_float2(aiv.y, aiv.y);
        ar2[k] = pf(cS,  aiy, pf(cR, ary, pf(cQ,  aix, pm(cP, arx))));
        ai2[k] = pf(cSn, ary, pf(cR, aiy, pf(cQn, arx, pm(cP, aix))));
    }
}

// CNOT chain: in-place bperm (no temp arrays at the pressure peak), then
// conditional half-swap (reg^32 on odd lanes), then static Gray relabel
// (pure SSA renaming, crosses float2 halves at compile time).
__device__ __forceinline__ void cnot_perm(float2 ar2[32], float2 ai2[32], int lane) {
    const int ga4 = (lane ^ (lane >> 1)) << 2;
#pragma unroll
    for (int k = 0; k < 32; ++k) {
        ar2[k] = make_float2(bperm(ga4, ar2[k].x), bperm(ga4, ar2[k].y));
        ai2[k] = make_float2(bperm(ga4, ai2[k].x), bperm(ga4, ai2[k].y));
    }
    const bool odd = lane & 1;
#pragma unroll
    for (int k = 0; k < 16; ++k) {
        const float2 a0 = ar2[k], a1 = ar2[k+16];
        ar2[k] = odd ? a1 : a0;  ar2[k+16] = odd ? a0 : a1;
        const float2 b0 = ai2[k], b1 = ai2[k+16];
        ai2[k] = odd ? b1 : b0;  ai2[k+16] = odd ? b0 : b1;
    }
    float2 nr[32], ni[32];
#pragma unroll
    for (int k = 0; k < 32; ++k) {
        const int g0 = (2*k)     ^ k;       // gray6(2k)
        const int g1 = (2*k + 1) ^ k;       // gray6(2k+1)
        nr[k] = make_float2(getc(ar2, g0), getc(ar2, g1));
        ni[k] = make_float2(getc(ai2, g0), getc(ai2, g1));
    }
#pragma unroll
    for (int k = 0; k < 32; ++k) { ar2[k] = nr[k]; ai2[k] = ni[k]; }
}

__global__ __launch_bounds__(256)
void qsim_kernel(const float* __restrict__ sb,   // (B,8) state_batch
                 const float* __restrict__ wts,  // (8,12,3) weights
                 const float* __restrict__ hw,   // (1,12) head_w
                 const float* __restrict__ hb,   // (1,) head_b
                 float* __restrict__ out,        // (B,)
                 int B) {
    const int lane   = threadIdx.x & 63;
    const int sample = blockIdx.x * 4 + (threadIdx.x >> 6);
    if (sample >= B) return;

    // ---- init to post-encoding state RX(x0)@w0, RY(x1)@w1 on |0..0>:
    // nonzero only at reg 0, lanes {0,16,32,48}.
    float c0, s0, c1, s1;
    __sincosf(0.5f * sb[sample*8 + 0], &s0, &c0);
    __sincosf(0.5f * sb[sample*8 + 1], &s1, &c1);
    float2 ar2[32], ai2[32];
#pragma unroll
    for (int k = 0; k < 32; ++k) { ar2[k] = make_float2(0.f, 0.f); ai2[k] = make_float2(0.f, 0.f); }
    {
        float a0 = 0.f, b0 = 0.f;
        if (lane == 0)  a0 =  c0*c1;
        if (lane == 16) a0 =  c0*s1;
        if (lane == 32) b0 = -s0*c1;
        if (lane == 48) b0 = -s0*s1;
        ar2[0].x = a0; ai2[0].x = b0;
    }

#pragma unroll 1
    for (int l = 0; l < 8; ++l) {
        const float* lw = wts + l*36;
        // wires 0..5 -> lane bits 5..0
#pragma unroll 1
        for (int w = 0; w < 6; ++w) {
            float A, Bc, C, D;
            rot_coeffs(lw[w*3+0], lw[w*3+1], lw[w*3+2], A, Bc, C, D);
            const int pb = 5 - w;
            const bool b = (lane >> pb) & 1;
            lane_gate(ar2, ai2, (lane ^ (1 << pb)) << 2,
                      A, b ? Bc : -Bc, b ? C : -C, -D);
        }
        // wires 6..11 -> reg bits 5..0
        { float A,Bc,C,D; rot_coeffs(lw[18],lw[19],lw[20],A,Bc,C,D); reg_gate_hi<4>(ar2,ai2,A,Bc,C,D); }
        { float A,Bc,C,D; rot_coeffs(lw[21],lw[22],lw[23],A,Bc,C,D); reg_gate_hi<3>(ar2,ai2,A,Bc,C,D); }
        { float A,Bc,C,D; rot_coeffs(lw[24],lw[25],lw[26],A,Bc,C,D); reg_gate_hi<2>(ar2,ai2,A,Bc,C,D); }
        { float A,Bc,C,D; rot_coeffs(lw[27],lw[28],lw[29],A,Bc,C,D); reg_gate_hi<1>(ar2,ai2,A,Bc,C,D); }
        { float A,Bc,C,D; rot_coeffs(lw[30],lw[31],lw[32],A,Bc,C,D); reg_gate_hi<0>(ar2,ai2,A,Bc,C,D); }
        { float A,Bc,C,D; rot_coeffs(lw[33],lw[34],lw[35],A,Bc,C,D); reg_gate_lo   (ar2,ai2,A,Bc,C,D); }
        if (l < 7) cnot_perm(ar2, ai2, lane);
    }

    // ---- epilogue (pre-last-CNOT state, prefix-parity sign masks):
    // wire w in 0..5 : sign = parity(lane >> (5-w))
    // wire w in 6..11: sign = parity(lane) * parity(r >> (11-w))
    float T = 0.f, S0=0.f,S1=0.f,S2=0.f,S3=0.f,S4=0.f,S5=0.f;
#pragma unroll
    for (int k = 0; k < 32; ++k) {
        const float2 p2 = pf(ai2[k], ai2[k], pm(ar2[k], ar2[k]));
#pragma unroll
        for (int h = 0; h < 2; ++h) {
            const int r = 2*k + h;
            const float p = h ? p2.y : p2.x;
            T  += p;
            S0 += (__builtin_popcount(r >> 0) & 1) ? -p : p;
            S1 += (__builtin_popcount(r >> 1) & 1) ? -p : p;
            S2 += (__builtin_popcount(r >> 2) & 1) ? -p : p;
            S3 += (__builtin_popcount(r >> 3) & 1) ? -p : p;
            S4 += (__builtin_popcount(r >> 4) & 1) ? -p : p;
            S5 += (__builtin_popcount(r >> 5) & 1) ? -p : p;
        }
    }
    float WL = 0.f;
#pragma unroll
    for (int w = 0; w < 6; ++w) {
        const float h = hw[w];
        WL += (__popc(lane >> (5 - w)) & 1) ? -h : h;
    }
    const float SR = hw[6]*S5 + hw[7]*S4 + hw[8]*S3
                   + hw[9]*S2 + hw[10]*S1 + hw[11]*S0;
    float u = T*WL + ((__popc(lane) & 1) ? -SR : SR);
#pragma unroll
    for (int off = 1; off < 64; off <<= 1)
        u += bperm((lane ^ off) << 2, u);
    if (lane == 0) out[sample] = u + hb[0];
}

extern "C" void kernel_launch(void* const* d_in, const int* in_sizes, int n_in,
                              void* d_out, int out_size, void* d_ws, size_t ws_size,
                              hipStream_t stream) {
    const float* sb  = (const float*)d_in[0];
    const float* wts = (const float*)d_in[1];
    const float* hw  = (const float*)d_in[2];
    const float* hb  = (const float*)d_in[3];
    float* out = (float*)d_out;
    const int B = in_sizes[0] / 8;            // (B,8) state_batch
    const int blocks = (B + 3) / 4;           // 4 waves (samples) per 256-thread block
    qsim_kernel<<<blocks, 256, 0, stream>>>(sb, wts, hw, hb, out, B);
}

// Round 4
// 535.736 us; speedup vs baseline: 23.3871x; 1.9746x over previous
//
#include <hip/hip_runtime.h>
#include <hip/hip_fp16.h>

// ---------------------------------------------------------------------------
// Batched 12-qubit state-vector sim, one wave (64 lanes) per sample.
// State: 4096 complex amps = 64 complex per lane, held in FP16 as __half2
// register arrays ar2[32], ai2[32] (element r = 2k+h lives in half h of
// half2 k). Packing element-pairs (coefficients uniform across elements)
// makes every gate update a v_pk_fma_f16 (same issue rate as v_pk_fma_f32),
// while HALVING both the ds_bpermute count (one b32 moves 2 elements) and
// the state VGPR footprint (128 -> 64 regs => 4-5 waves/SIMD occupancy).
// Round-3 evidence: fp32 version was jointly VALU (53%) + DS (~45%) bound
// at 2-3 waves/SIMD; DS inst floor ~470us, VALU ~560us, dur 1058us.
// fp16 error budget: ~1e-2 relative per amplitude after 98 gates, but
// expval sums 4096 probs with random-sign errors -> output error ~3e-4,
// well under the 3.46e-3 threshold.
// Flat index y (12 bits) = (lane<<6) | reg.  Wire w <-> flat bit p = 11-w.
//   wires 0..5  -> lane bits 5..0  (cross-lane gates via ds_bpermute)
//   wires 6..11 -> reg  bits 5..0  (in-register gates)
// CNOT chain (ctrl=i,tgt=i+1) == new[d] = old[d ^ (d>>1)]:
//   new[l][r] = old[gray(l)][gray6(r) ^ 32*(l&1)]
// Last layer's CNOT is elided: folded into epilogue prefix-parity sign masks.
// Rot(phi,th,om) = [[(A,-B),(-C,-D)],[(C,-D),(A,B)]], A=ca*ch B=sa*ch
// C=cb*sh D=sb*sh.
// NO min-waves launch bound: round 2 showed capping VGPR below state+temps
// spills the whole state to scratch (FETCH 373KB -> 14.7GB, 8.4x slower).
// ---------------------------------------------------------------------------

typedef __half2 h2;

__device__ __forceinline__ h2 bperm2(int addr4, h2 v) {
    int x = __builtin_amdgcn_ds_bpermute(addr4, __builtin_bit_cast(int, v));
    return __builtin_bit_cast(h2, x);
}
__device__ __forceinline__ float bpermf(int addr4, float v) {
    return __int_as_float(__builtin_amdgcn_ds_bpermute(addr4, __float_as_int(v)));
}
// compile-time half access (idx constant after unroll)
__device__ __forceinline__ __half geth(const h2 a[32], int idx) {
    return (idx & 1) ? __high2half(a[idx >> 1]) : __low2half(a[idx >> 1]);
}

__device__ __forceinline__ void rot_coeffs(float phi, float th, float om,
                                           float& A, float& B, float& C, float& D) {
    float ch, sh, ca, sa, cb, sb;
    __sincosf(0.5f*th,       &sh, &ch);
    __sincosf(0.5f*(phi+om), &sa, &ca);
    __sincosf(0.5f*(phi-om), &sb, &cb);
    A = ca*ch; B = sa*ch; C = cb*sh; D = sb*sh;
}

// Gate on a LANE bit. out = cs*x + co*partner, per-lane scalar coefficients
// splat to both halves. Software-pipelined bperm prefetch (CH half2s/chunk).
__device__ __forceinline__ void lane_gate(h2 ar2[32], h2 ai2[32], int addr4,
                                          float csrF, float csiF, float corF, float coiF) {
    const h2 csr  = __float2half2_rn(csrF),  csi  = __float2half2_rn(csiF);
    const h2 cor  = __float2half2_rn(corF),  coi  = __float2half2_rn(coiF);
    const h2 ncsi = __float2half2_rn(-csiF), ncoi = __float2half2_rn(-coiF);
    constexpr int CH = 4;
    h2 tr[CH], ti[CH], pr[CH], pi[CH];
#pragma unroll
    for (int k = 0; k < CH; ++k) {
        tr[k] = bperm2(addr4, ar2[k]);
        ti[k] = bperm2(addr4, ai2[k]);
    }
#pragma unroll
    for (int base = 0; base < 32; base += CH) {
        if (base + CH < 32) {
#pragma unroll
            for (int k = 0; k < CH; ++k) {
                pr[k] = bperm2(addr4, ar2[base+CH+k]);
                pi[k] = bperm2(addr4, ai2[base+CH+k]);
            }
        }
#pragma unroll
        for (int k = 0; k < CH; ++k) {
            const int r = base + k;
            const h2 xr = ar2[r], xi = ai2[r];
            // ar = csr*xr - csi*xi + cor*tr - coi*ti
            ar2[r] = __hfma2(ncoi, ti[k], __hfma2(cor, tr[k], __hfma2(ncsi, xi, __hmul2(csr, xr))));
            // ai = csr*xi + csi*xr + cor*ti + coi*tr
            ai2[r] = __hfma2( coi, tr[k], __hfma2(cor, ti[k], __hfma2( csi, xr, __hmul2(csr, xi))));
        }
#pragma unroll
        for (int k = 0; k < CH; ++k) { tr[k] = pr[k]; ti[k] = pi[k]; }
    }
}

// Gate on reg bit P>=1 (half2-index bit P2=P-1): pairs of whole half2s.
template<int P2>
__device__ __forceinline__ void reg_gate_hi(h2 ar2[32], h2 ai2[32],
                                            float Af, float Bf, float Cf, float Df) {
    const h2 A  = __float2half2_rn(Af),  B  = __float2half2_rn(Bf);
    const h2 C  = __float2half2_rn(Cf),  D  = __float2half2_rn(Df);
    const h2 nB = __float2half2_rn(-Bf), nC = __float2half2_rn(-Cf);
    const h2 nD = __float2half2_rn(-Df);
#pragma unroll
    for (int k0 = 0; k0 < 32; ++k0) {
        if (k0 & (1 << P2)) continue;          // compile-time filtered
        const int k1 = k0 | (1 << P2);
        const h2 a0r = ar2[k0], a0i = ai2[k0], a1r = ar2[k1], a1i = ai2[k1];
        ar2[k0] = __hfma2( D, a1i, __hfma2(nC, a1r, __hfma2( B, a0i, __hmul2(A, a0r))));
        ai2[k0] = __hfma2(nD, a1r, __hfma2(nC, a1i, __hfma2(nB, a0r, __hmul2(A, a0i))));
        ar2[k1] = __hfma2(nB, a1i, __hfma2( A, a1r, __hfma2( D, a0i, __hmul2(C, a0r))));
        ai2[k1] = __hfma2( B, a1r, __hfma2( A, a1i, __hfma2(nD, a0r, __hmul2(C, a0i))));
    }
}

// Gate on reg bit 0: pair lives inside one half2. Per-half coefficient
// pairs + half-broadcasts keep it packed.
__device__ __forceinline__ void reg_gate_lo(h2 ar2[32], h2 ai2[32],
                                            float A, float B, float C, float D) {
    const h2 cP  = __halves2half2(__float2half( A), __float2half( C));
    const h2 cQ  = __halves2half2(__float2half( B), __float2half( D));
    const h2 cR  = __halves2half2(__float2half(-C), __float2half( A));
    const h2 cS  = __halves2half2(__float2half( D), __float2half(-B));
    const h2 cQn = __halves2half2(__float2half(-B), __float2half(-D));
    const h2 cSn = __halves2half2(__float2half(-D), __float2half( B));
#pragma unroll
    for (int k = 0; k < 32; ++k) {
        const h2 arv = ar2[k], aiv = ai2[k];
        const h2 arx = __low2half2(arv), ary = __high2half2(arv);
        const h2 aix = __low2half2(aiv), aiy = __high2half2(aiv);
        ar2[k] = __hfma2(cS,  aiy, __hfma2(cR, ary, __hfma2(cQ,  aix, __hmul2(cP, arx))));
        ai2[k] = __hfma2(cSn, ary, __hfma2(cR, aiy, __hfma2(cQn, arx, __hmul2(cP, aix))));
    }
}

// CNOT chain: in-place bperm (lane move), then conditional half-swap
// (reg^32 on odd lanes), then static Gray relabel (compile-time, crosses
// half2 halves via v_perm-style repacks).
__device__ __forceinline__ void cnot_perm(h2 ar2[32], h2 ai2[32], int lane) {
    const int ga4 = (lane ^ (lane >> 1)) << 2;
#pragma unroll
    for (int k = 0; k < 32; ++k) {
        ar2[k] = bperm2(ga4, ar2[k]);
        ai2[k] = bperm2(ga4, ai2[k]);
    }
    const bool odd = lane & 1;
#pragma unroll
    for (int k = 0; k < 16; ++k) {
        const h2 a0 = ar2[k], a1 = ar2[k+16];
        ar2[k] = odd ? a1 : a0;  ar2[k+16] = odd ? a0 : a1;
        const h2 b0 = ai2[k], b1 = ai2[k+16];
        ai2[k] = odd ? b1 : b0;  ai2[k+16] = odd ? b0 : b1;
    }
    h2 nr[32], ni[32];
#pragma unroll
    for (int k = 0; k < 32; ++k) {
        const int g0 = (2*k)     ^ k;       // gray6(2k)
        const int g1 = (2*k + 1) ^ k;       // gray6(2k+1)
        nr[k] = __halves2half2(geth(ar2, g0), geth(ar2, g1));
        ni[k] = __halves2half2(geth(ai2, g0), geth(ai2, g1));
    }
#pragma unroll
    for (int k = 0; k < 32; ++k) { ar2[k] = nr[k]; ai2[k] = ni[k]; }
}

__global__ __launch_bounds__(256)
void qsim_kernel(const float* __restrict__ sb,   // (B,8) state_batch
                 const float* __restrict__ wts,  // (8,12,3) weights
                 const float* __restrict__ hw,   // (1,12) head_w
                 const float* __restrict__ hb,   // (1,) head_b
                 float* __restrict__ out,        // (B,)
                 int B) {
    const int lane   = threadIdx.x & 63;
    const int sample = blockIdx.x * 4 + (threadIdx.x >> 6);
    if (sample >= B) return;

    // ---- init to post-encoding state RX(x0)@w0, RY(x1)@w1 on |0..0>:
    // nonzero only at reg 0, lanes {0,16,32,48}.
    float c0, s0, c1, s1;
    __sincosf(0.5f * sb[sample*8 + 0], &s0, &c0);
    __sincosf(0.5f * sb[sample*8 + 1], &s1, &c1);
    h2 ar2[32], ai2[32];
    const h2 zero = __float2half2_rn(0.f);
#pragma unroll
    for (int k = 0; k < 32; ++k) { ar2[k] = zero; ai2[k] = zero; }
    {
        float a0 = 0.f, b0 = 0.f;
        if (lane == 0)  a0 =  c0*c1;
        if (lane == 16) a0 =  c0*s1;
        if (lane == 32) b0 = -s0*c1;
        if (lane == 48) b0 = -s0*s1;
        ar2[0] = __floats2half2_rn(a0, 0.f);
        ai2[0] = __floats2half2_rn(b0, 0.f);
    }

#pragma unroll 1
    for (int l = 0; l < 8; ++l) {
        const float* lw = wts + l*36;
        // wires 0..5 -> lane bits 5..0
#pragma unroll 1
        for (int w = 0; w < 6; ++w) {
            float A, Bc, C, D;
            rot_coeffs(lw[w*3+0], lw[w*3+1], lw[w*3+2], A, Bc, C, D);
            const int pb = 5 - w;
            const bool b = (lane >> pb) & 1;
            lane_gate(ar2, ai2, (lane ^ (1 << pb)) << 2,
                      A, b ? Bc : -Bc, b ? C : -C, -D);
        }
        // wires 6..11 -> reg bits 5..0
        { float A,Bc,C,D; rot_coeffs(lw[18],lw[19],lw[20],A,Bc,C,D); reg_gate_hi<4>(ar2,ai2,A,Bc,C,D); }
        { float A,Bc,C,D; rot_coeffs(lw[21],lw[22],lw[23],A,Bc,C,D); reg_gate_hi<3>(ar2,ai2,A,Bc,C,D); }
        { float A,Bc,C,D; rot_coeffs(lw[24],lw[25],lw[26],A,Bc,C,D); reg_gate_hi<2>(ar2,ai2,A,Bc,C,D); }
        { float A,Bc,C,D; rot_coeffs(lw[27],lw[28],lw[29],A,Bc,C,D); reg_gate_hi<1>(ar2,ai2,A,Bc,C,D); }
        { float A,Bc,C,D; rot_coeffs(lw[30],lw[31],lw[32],A,Bc,C,D); reg_gate_hi<0>(ar2,ai2,A,Bc,C,D); }
        { float A,Bc,C,D; rot_coeffs(lw[33],lw[34],lw[35],A,Bc,C,D); reg_gate_lo   (ar2,ai2,A,Bc,C,D); }
        if (l < 7) cnot_perm(ar2, ai2, lane);
    }

    // ---- epilogue in fp32 (pre-last-CNOT state, prefix-parity sign masks):
    // wire w in 0..5 : sign = parity(lane >> (5-w))
    // wire w in 6..11: sign = parity(lane) * parity(r >> (11-w))
    float T = 0.f, S0=0.f,S1=0.f,S2=0.f,S3=0.f,S4=0.f,S5=0.f;
#pragma unroll
    for (int k = 0; k < 32; ++k) {
        const float2 rr = __half22float2(ar2[k]);
        const float2 ii = __half22float2(ai2[k]);
        const float px = rr.x*rr.x + ii.x*ii.x;
        const float py = rr.y*rr.y + ii.y*ii.y;
#pragma unroll
        for (int h = 0; h < 2; ++h) {
            const int r = 2*k + h;
            const float p = h ? py : px;
            T  += p;
            S0 += (__builtin_popcount(r >> 0) & 1) ? -p : p;
            S1 += (__builtin_popcount(r >> 1) & 1) ? -p : p;
            S2 += (__builtin_popcount(r >> 2) & 1) ? -p : p;
            S3 += (__builtin_popcount(r >> 3) & 1) ? -p : p;
            S4 += (__builtin_popcount(r >> 4) & 1) ? -p : p;
            S5 += (__builtin_popcount(r >> 5) & 1) ? -p : p;
        }
    }
    float WL = 0.f;
#pragma unroll
    for (int w = 0; w < 6; ++w) {
        const float h = hw[w];
        WL += (__popc(lane >> (5 - w)) & 1) ? -h : h;
    }
    const float SR = hw[6]*S5 + hw[7]*S4 + hw[8]*S3
                   + hw[9]*S2 + hw[10]*S1 + hw[11]*S0;
    float u = T*WL + ((__popc(lane) & 1) ? -SR : SR);
#pragma unroll
    for (int off = 1; off < 64; off <<= 1)
        u += bpermf((lane ^ off) << 2, u);
    if (lane == 0) out[sample] = u + hb[0];
}

extern "C" void kernel_launch(void* const* d_in, const int* in_sizes, int n_in,
                              void* d_out, int out_size, void* d_ws, size_t ws_size,
                              hipStream_t stream) {
    const float* sb  = (const float*)d_in[0];
    const float* wts = (const float*)d_in[1];
    const float* hw  = (const float*)d_in[2];
    const float* hb  = (const float*)d_in[3];
    float* out = (float*)d_out;
    const int B = in_sizes[0] / 8;            // (B,8) state_batch
    const int blocks = (B + 3) / 4;           // 4 waves (samples) per 256-thread block
    qsim_kernel<<<blocks, 256, 0, stream>>>(sb, wts, hw, hb, out, B);
}

// Round 5
// 508.977 us; speedup vs baseline: 24.6166x; 1.0526x over previous
//
#include <hip/hip_runtime.h>
#include <hip/hip_fp16.h>

// ---------------------------------------------------------------------------
// Batched 12-qubit state-vector sim, one wave (64 lanes) per sample.
// State: 4096 complex amps = 64 complex/lane, FP16 __half2-packed: element
// r = 2k+h in half h of ar2[k]/ai2[k]. Every gate update is v_pk_fma_f16.
// Flat index y = (logical_lane<<6) | reg.  Wire w <-> flat bit p = 11-w.
//   wires 0..5  -> lane bits (cross-lane via ds_bpermute)
//   wires 6..11 -> reg bits (in-register)
// CNOT chain == new[d] = old[d ^ (d>>1)]. Its LANE part (gray map G, linear
// over GF(2)) is DEFERRED, not executed: lanes keep data; physical lane l
// holds logical lane p = pi(l). Each lane-gate's partner mask becomes
// Minv[pb] = pi^-1(1<<pb) (still one XOR, by linearity); coefficient-select
// reads bit pb of p; epilogue sign masks use p. Per layer: p = Ginv(p),
// Minv[pb] ^= Minv[pb-1] (descending). This kills 64 bperms/layer (448 of
// 3520 DS ops). The REG part (gray6 relabel + conditional ^32 on
// parity(p_old)) stays physical: compile-time relabel + 64 cndmask.
// Last layer's CNOT fully elided via epilogue prefix-parity sign masks.
// Rot(phi,th,om) = [[(A,-B),(-C,-D)],[(C,-D),(A,B)]], A=ca*ch B=sa*ch
// C=cb*sh D=sb*sh.
// Block=64 (1 wave): residency-granularity probe for the occupancy mystery.
// NO min-waves launch bound: round 2 showed capping VGPR below state+temps
// spills everything (FETCH 373KB -> 14.7GB, 8.4x slower).
// ---------------------------------------------------------------------------

typedef __half2 h2;

__device__ __forceinline__ h2 bperm2(int addr4, h2 v) {
    int x = __builtin_amdgcn_ds_bpermute(addr4, __builtin_bit_cast(int, v));
    return __builtin_bit_cast(h2, x);
}
__device__ __forceinline__ float bpermf(int addr4, float v) {
    return __int_as_float(__builtin_amdgcn_ds_bpermute(addr4, __float_as_int(v)));
}
// compile-time half access (idx constant after unroll)
__device__ __forceinline__ __half geth(const h2 a[32], int idx) {
    return (idx & 1) ? __high2half(a[idx >> 1]) : __low2half(a[idx >> 1]);
}
// inverse gray map on 6 bits: G(x)=x^(x>>1); Ginv(y)=y^(y>>1)^...^(y>>5)
__device__ __forceinline__ int ginv6(int y) {
    return (y ^ (y >> 1) ^ (y >> 2) ^ (y >> 3) ^ (y >> 4) ^ (y >> 5)) & 63;
}

__device__ __forceinline__ void rot_coeffs(float phi, float th, float om,
                                           float& A, float& B, float& C, float& D) {
    float ch, sh, ca, sa, cb, sb;
    __sincosf(0.5f*th,       &sh, &ch);
    __sincosf(0.5f*(phi+om), &sa, &ca);
    __sincosf(0.5f*(phi-om), &sb, &cb);
    A = ca*ch; B = sa*ch; C = cb*sh; D = sb*sh;
}

// Gate on a (logical) lane bit. out = cs*x + co*partner; partner fetched from
// physical lane (lane ^ Minv). Software-pipelined bperm prefetch.
__device__ __forceinline__ void lane_gate(h2 ar2[32], h2 ai2[32], int addr4,
                                          float csrF, float csiF, float corF, float coiF) {
    const h2 csr  = __float2half2_rn(csrF),  csi  = __float2half2_rn(csiF);
    const h2 cor  = __float2half2_rn(corF),  coi  = __float2half2_rn(coiF);
    const h2 ncsi = __float2half2_rn(-csiF), ncoi = __float2half2_rn(-coiF);
    constexpr int CH = 4;
    h2 tr[CH], ti[CH], pr[CH], pi[CH];
#pragma unroll
    for (int k = 0; k < CH; ++k) {
        tr[k] = bperm2(addr4, ar2[k]);
        ti[k] = bperm2(addr4, ai2[k]);
    }
#pragma unroll
    for (int base = 0; base < 32; base += CH) {
        if (base + CH < 32) {
#pragma unroll
            for (int k = 0; k < CH; ++k) {
                pr[k] = bperm2(addr4, ar2[base+CH+k]);
                pi[k] = bperm2(addr4, ai2[base+CH+k]);
            }
        }
#pragma unroll
        for (int k = 0; k < CH; ++k) {
            const int r = base + k;
            const h2 xr = ar2[r], xi = ai2[r];
            ar2[r] = __hfma2(ncoi, ti[k], __hfma2(cor, tr[k], __hfma2(ncsi, xi, __hmul2(csr, xr))));
            ai2[r] = __hfma2( coi, tr[k], __hfma2(cor, ti[k], __hfma2( csi, xr, __hmul2(csr, xi))));
        }
#pragma unroll
        for (int k = 0; k < CH; ++k) { tr[k] = pr[k]; ti[k] = pi[k]; }
    }
}

// Gate on reg bit P>=1 (half2-index bit P2=P-1): pairs of whole half2s.
template<int P2>
__device__ __forceinline__ void reg_gate_hi(h2 ar2[32], h2 ai2[32],
                                            float Af, float Bf, float Cf, float Df) {
    const h2 A  = __float2half2_rn(Af),  B  = __float2half2_rn(Bf);
    const h2 C  = __float2half2_rn(Cf),  D  = __float2half2_rn(Df);
    const h2 nB = __float2half2_rn(-Bf), nC = __float2half2_rn(-Cf);
    const h2 nD = __float2half2_rn(-Df);
#pragma unroll
    for (int k0 = 0; k0 < 32; ++k0) {
        if (k0 & (1 << P2)) continue;          // compile-time filtered
        const int k1 = k0 | (1 << P2);
        const h2 a0r = ar2[k0], a0i = ai2[k0], a1r = ar2[k1], a1i = ai2[k1];
        ar2[k0] = __hfma2( D, a1i, __hfma2(nC, a1r, __hfma2( B, a0i, __hmul2(A, a0r))));
        ai2[k0] = __hfma2(nD, a1r, __hfma2(nC, a1i, __hfma2(nB, a0r, __hmul2(A, a0i))));
        ar2[k1] = __hfma2(nB, a1i, __hfma2( A, a1r, __hfma2( D, a0i, __hmul2(C, a0r))));
        ai2[k1] = __hfma2( B, a1r, __hfma2( A, a1i, __hfma2(nD, a0r, __hmul2(C, a0i))));
    }
}

// Gate on reg bit 0: pair lives inside one half2.
__device__ __forceinline__ void reg_gate_lo(h2 ar2[32], h2 ai2[32],
                                            float A, float B, float C, float D) {
    const h2 cP  = __halves2half2(__float2half( A), __float2half( C));
    const h2 cQ  = __halves2half2(__float2half( B), __float2half( D));
    const h2 cR  = __halves2half2(__float2half(-C), __float2half( A));
    const h2 cS  = __halves2half2(__float2half( D), __float2half(-B));
    const h2 cQn = __halves2half2(__float2half(-B), __float2half(-D));
    const h2 cSn = __halves2half2(__float2half(-D), __float2half( B));
#pragma unroll
    for (int k = 0; k < 32; ++k) {
        const h2 arv = ar2[k], aiv = ai2[k];
        const h2 arx = __low2half2(arv), ary = __high2half2(arv);
        const h2 aix = __low2half2(aiv), aiy = __high2half2(aiv);
        ar2[k] = __hfma2(cS,  aiy, __hfma2(cR, ary, __hfma2(cQ,  aix, __hmul2(cP, arx))));
        ai2[k] = __hfma2(cSn, ary, __hfma2(cR, aiy, __hfma2(cQn, arx, __hmul2(cP, aix))));
    }
}

// CNOT reg-part only (lane-part deferred): value_new[r] = value_old[gray6(r)^32c],
// c = parity of OLD logical lane. Conditional half-swap + compile-time relabel.
__device__ __forceinline__ void cnot_reg_part(h2 ar2[32], h2 ai2[32], int c) {
#pragma unroll
    for (int k = 0; k < 16; ++k) {
        const h2 a0 = ar2[k], a1 = ar2[k+16];
        ar2[k] = c ? a1 : a0;  ar2[k+16] = c ? a0 : a1;
        const h2 b0 = ai2[k], b1 = ai2[k+16];
        ai2[k] = c ? b1 : b0;  ai2[k+16] = c ? b0 : b1;
    }
    h2 nr[32], ni[32];
#pragma unroll
    for (int k = 0; k < 32; ++k) {
        const int g0 = (2*k)     ^ k;       // gray6(2k)
        const int g1 = (2*k + 1) ^ k;       // gray6(2k+1)
        nr[k] = __halves2half2(geth(ar2, g0), geth(ar2, g1));
        ni[k] = __halves2half2(geth(ai2, g0), geth(ai2, g1));
    }
#pragma unroll
    for (int k = 0; k < 32; ++k) { ar2[k] = nr[k]; ai2[k] = ni[k]; }
}

__global__ __launch_bounds__(64)
void qsim_kernel(const float* __restrict__ sb,   // (B,8) state_batch
                 const float* __restrict__ wts,  // (8,12,3) weights
                 const float* __restrict__ hw,   // (1,12) head_w
                 const float* __restrict__ hb,   // (1,) head_b
                 float* __restrict__ out) {      // (B,)
    const int lane   = threadIdx.x;              // block = 1 wave
    const int sample = blockIdx.x;

    // ---- init to post-encoding state RX(x0)@w0, RY(x1)@w1 on |0..0>:
    // nonzero only at reg 0, (logical==physical at t=0) lanes {0,16,32,48}.
    float c0, s0, c1, s1;
    __sincosf(0.5f * sb[sample*8 + 0], &s0, &c0);
    __sincosf(0.5f * sb[sample*8 + 1], &s1, &c1);
    h2 ar2[32], ai2[32];
    const h2 zero = __float2half2_rn(0.f);
#pragma unroll
    for (int k = 0; k < 32; ++k) { ar2[k] = zero; ai2[k] = zero; }
    {
        float a0 = 0.f, b0 = 0.f;
        if (lane == 0)  a0 =  c0*c1;
        if (lane == 16) a0 =  c0*s1;
        if (lane == 32) b0 = -s0*c1;
        if (lane == 48) b0 = -s0*s1;
        ar2[0] = __floats2half2_rn(a0, 0.f);
        ai2[0] = __floats2half2_rn(b0, 0.f);
    }

    int p = lane;                                  // logical lane = pi(lane)
    int Minv[6] = {1, 2, 4, 8, 16, 32};            // Minv[pb] = pi^-1(1<<pb)

#pragma unroll 1
    for (int l = 0; l < 8; ++l) {
        const float* lw = wts + l*36;
        // wires 0..5 -> logical lane bits 5..0
#pragma unroll
        for (int w = 0; w < 6; ++w) {
            float A, Bc, C, D;
            rot_coeffs(lw[w*3+0], lw[w*3+1], lw[w*3+2], A, Bc, C, D);
            const int pb = 5 - w;
            const bool b = (p >> pb) & 1;
            lane_gate(ar2, ai2, (lane ^ Minv[pb]) << 2,
                      A, b ? Bc : -Bc, b ? C : -C, -D);
        }
        // wires 6..11 -> reg bits 5..0
        { float A,Bc,C,D; rot_coeffs(lw[18],lw[19],lw[20],A,Bc,C,D); reg_gate_hi<4>(ar2,ai2,A,Bc,C,D); }
        { float A,Bc,C,D; rot_coeffs(lw[21],lw[22],lw[23],A,Bc,C,D); reg_gate_hi<3>(ar2,ai2,A,Bc,C,D); }
        { float A,Bc,C,D; rot_coeffs(lw[24],lw[25],lw[26],A,Bc,C,D); reg_gate_hi<2>(ar2,ai2,A,Bc,C,D); }
        { float A,Bc,C,D; rot_coeffs(lw[27],lw[28],lw[29],A,Bc,C,D); reg_gate_hi<1>(ar2,ai2,A,Bc,C,D); }
        { float A,Bc,C,D; rot_coeffs(lw[30],lw[31],lw[32],A,Bc,C,D); reg_gate_hi<0>(ar2,ai2,A,Bc,C,D); }
        { float A,Bc,C,D; rot_coeffs(lw[33],lw[34],lw[35],A,Bc,C,D); reg_gate_lo   (ar2,ai2,A,Bc,C,D); }
        if (l < 7) {
            // CNOT: reg part physical, lane part deferred into p/Minv.
            const int c = __popc(p) & 1;           // parity of OLD logical lane
            cnot_reg_part(ar2, ai2, c);
            p = ginv6(p);                          // pi_new = Ginv o pi_old
#pragma unroll
            for (int pb = 5; pb >= 1; --pb) Minv[pb] ^= Minv[pb-1];  // pi_new^-1 = pi_old^-1 o G
        }
    }

    // ---- epilogue (pre-last-CNOT state, prefix-parity sign masks, logical
    // lane = p):  wire w in 0..5: sign = parity(p >> (5-w));
    //             wire w in 6..11: sign = parity(p) * parity(r >> (11-w))
    float T = 0.f, S0=0.f,S1=0.f,S2=0.f,S3=0.f,S4=0.f,S5=0.f;
#pragma unroll
    for (int k = 0; k < 32; ++k) {
        const float2 rr = __half22float2(ar2[k]);
        const float2 ii = __half22float2(ai2[k]);
        const float px = rr.x*rr.x + ii.x*ii.x;
        const float py = rr.y*rr.y + ii.y*ii.y;
#pragma unroll
        for (int h = 0; h < 2; ++h) {
            const int r = 2*k + h;
            const float pv = h ? py : px;
            T  += pv;
            S0 += (__builtin_popcount(r >> 0) & 1) ? -pv : pv;
            S1 += (__builtin_popcount(r >> 1) & 1) ? -pv : pv;
            S2 += (__builtin_popcount(r >> 2) & 1) ? -pv : pv;
            S3 += (__builtin_popcount(r >> 3) & 1) ? -pv : pv;
            S4 += (__builtin_popcount(r >> 4) & 1) ? -pv : pv;
            S5 += (__builtin_popcount(r >> 5) & 1) ? -pv : pv;
        }
    }
    float WL = 0.f;
#pragma unroll
    for (int w = 0; w < 6; ++w) {
        const float hwv = hw[w];
        WL += (__popc(p >> (5 - w)) & 1) ? -hwv : hwv;
    }
    const float SR = hw[6]*S5 + hw[7]*S4 + hw[8]*S3
                   + hw[9]*S2 + hw[10]*S1 + hw[11]*S0;
    float u = T*WL + ((__popc(p) & 1) ? -SR : SR);
#pragma unroll
    for (int off = 1; off < 64; off <<= 1)
        u += bpermf((lane ^ off) << 2, u);
    if (lane == 0) out[sample] = u + hb[0];
}

extern "C" void kernel_launch(void* const* d_in, const int* in_sizes, int n_in,
                              void* d_out, int out_size, void* d_ws, size_t ws_size,
                              hipStream_t stream) {
    const float* sb  = (const float*)d_in[0];
    const float* wts = (const float*)d_in[1];
    const float* hw  = (const float*)d_in[2];
    const float* hb  = (const float*)d_in[3];
    float* out = (float*)d_out;
    const int B = in_sizes[0] / 8;            // (B,8) state_batch
    qsim_kernel<<<B, 64, 0, stream>>>(sb, wts, hw, hb, out);
}

// Round 6
// 487.764 us; speedup vs baseline: 25.6872x; 1.0435x over previous
//
#include <hip/hip_runtime.h>
#include <hip/hip_fp16.h>

// ---------------------------------------------------------------------------
// Batched 12-qubit state-vector sim, one wave (64 lanes) per sample.
// State: 4096 complex amps = 64 complex/lane, FP16 __half2-packed: element
// r = 2k+h in half h of ar2[k]/ai2[k]. Every gate update is v_pk_fma_f16.
// Flat index y = (logical_lane<<6) | reg.  Wire w <-> flat bit p = 11-w.
//   wires 0..5  -> lane bits (cross-lane via ds_bpermute)
//   wires 6..11 -> reg bits (in-register)
// CNOT chain == new[d] = old[d ^ (d>>1)]. LANE part (linear gray map) is
// DEFERRED into (p, Minv[]) bookkeeping; REG part (gray6 relabel + ^32 on
// parity(p_old)) is physical. Last layer's CNOT elided via epilogue
// prefix-parity sign masks.
// ROUND 6: all 96 gates' Rot coefficients (batch-shared!) are computed ONCE
// by a 1-block pre-kernel into a 3KB table in d_ws, pre-packed as splatted
// __half2 incl. negated variants. Main kernel s_loads records (scalar pipe,
// wave-uniform) -> kills 288 sincos + ~1.2k cvt/pack VALU inst per wave and
// the serial trig->gate dependency stall before every gate.
// Rot(phi,th,om) = [[(A,-B),(-C,-D)],[(C,-D),(A,B)]], A=ca*ch B=sa*ch
// C=cb*sh D=sb*sh.
// NO min-waves launch bound: round 2 showed capping VGPR below state+temps
// spills everything (FETCH 373KB -> 14.7GB, 8.4x slower).
// ---------------------------------------------------------------------------

typedef __half2 h2;

struct GateRec {            // 32 B, one per gate
    h2 a, b, c, d;          // splat(A),splat(B),splat(C),splat(D)   [w<11]
    h2 nb, nc, nd, pad;     // splat(-B),splat(-C),splat(-D)
};                          // w==11 (intra-half2): a..nc = cP,cQ,cR,cS,cQn,cSn

__device__ __forceinline__ h2 bperm2(int addr4, h2 v) {
    int x = __builtin_amdgcn_ds_bpermute(addr4, __builtin_bit_cast(int, v));
    return __builtin_bit_cast(h2, x);
}
__device__ __forceinline__ float bpermf(int addr4, float v) {
    return __int_as_float(__builtin_amdgcn_ds_bpermute(addr4, __float_as_int(v)));
}
__device__ __forceinline__ __half geth(const h2 a[32], int idx) {
    return (idx & 1) ? __high2half(a[idx >> 1]) : __low2half(a[idx >> 1]);
}
__device__ __forceinline__ int ginv6(int y) {
    return (y ^ (y >> 1) ^ (y >> 2) ^ (y >> 3) ^ (y >> 4) ^ (y >> 5)) & 63;
}
__device__ __forceinline__ h2 pack2f(float x, float y) {
    return __halves2half2(__float2half(x), __float2half(y));
}

// ---- pre-kernel: gate-coefficient table (96 gates, batch-shared) ----------
__global__ void coeff_kernel(const float* __restrict__ wts, GateRec* __restrict__ tbl) {
    const int g = threadIdx.x;
    if (g >= 96) return;
    const int l = g / 12, w = g % 12;
    const float* lw = wts + l*36 + w*3;
    const float phi = lw[0], th = lw[1], om = lw[2];
    float ch, sh, ca, sa, cb, sb;
    __sincosf(0.5f*th,       &sh, &ch);
    __sincosf(0.5f*(phi+om), &sa, &ca);
    __sincosf(0.5f*(phi-om), &sb, &cb);
    const float A = ca*ch, B = sa*ch, C = cb*sh, D = sb*sh;
    GateRec r;
    if (w == 11) {          // intra-half2 gate: mixed-pair constants
        r.a  = pack2f( A,  C);   // cP
        r.b  = pack2f( B,  D);   // cQ
        r.c  = pack2f(-C,  A);   // cR
        r.d  = pack2f( D, -B);   // cS
        r.nb = pack2f(-B, -D);   // cQn
        r.nc = pack2f(-D,  B);   // cSn
        r.nd = pack2f(0.f, 0.f); r.pad = pack2f(0.f, 0.f);
    } else {
        r.a  = pack2f( A,  A); r.b  = pack2f( B,  B);
        r.c  = pack2f( C,  C); r.d  = pack2f( D,  D);
        r.nb = pack2f(-B, -B); r.nc = pack2f(-C, -C);
        r.nd = pack2f(-D, -D); r.pad = pack2f(0.f, 0.f);
    }
    tbl[g] = r;
}

// Gate on a (logical) lane bit. out = cs*x + co*partner; partner fetched from
// physical lane (lane ^ Minv). Coefficients pre-selected h2 (from SGPR recs).
__device__ __forceinline__ void lane_gate(h2 ar2[32], h2 ai2[32], int addr4,
                                          h2 csr, h2 csi, h2 ncsi,
                                          h2 cor, h2 coi, h2 ncoi) {
    constexpr int CH = 4;
    h2 tr[CH], ti[CH], pr[CH], pi[CH];
#pragma unroll
    for (int k = 0; k < CH; ++k) {
        tr[k] = bperm2(addr4, ar2[k]);
        ti[k] = bperm2(addr4, ai2[k]);
    }
#pragma unroll
    for (int base = 0; base < 32; base += CH) {
        if (base + CH < 32) {
#pragma unroll
            for (int k = 0; k < CH; ++k) {
                pr[k] = bperm2(addr4, ar2[base+CH+k]);
                pi[k] = bperm2(addr4, ai2[base+CH+k]);
            }
        }
#pragma unroll
        for (int k = 0; k < CH; ++k) {
            const int r = base + k;
            const h2 xr = ar2[r], xi = ai2[r];
            // ar = csr*xr - csi*xi + cor*tr - coi*ti
            ar2[r] = __hfma2(ncoi, ti[k], __hfma2(cor, tr[k], __hfma2(ncsi, xi, __hmul2(csr, xr))));
            // ai = csr*xi + csi*xr + cor*ti + coi*tr
            ai2[r] = __hfma2( coi, tr[k], __hfma2(cor, ti[k], __hfma2( csi, xr, __hmul2(csr, xi))));
        }
#pragma unroll
        for (int k = 0; k < CH; ++k) { tr[k] = pr[k]; ti[k] = pi[k]; }
    }
}

// Gate on reg bit P>=1 (half2-index bit P2=P-1): pairs of whole half2s.
template<int P2>
__device__ __forceinline__ void reg_gate_hi(h2 ar2[32], h2 ai2[32], const GateRec& R) {
#pragma unroll
    for (int k0 = 0; k0 < 32; ++k0) {
        if (k0 & (1 << P2)) continue;          // compile-time filtered
        const int k1 = k0 | (1 << P2);
        const h2 a0r = ar2[k0], a0i = ai2[k0], a1r = ar2[k1], a1i = ai2[k1];
        ar2[k0] = __hfma2(R.d,  a1i, __hfma2(R.nc, a1r, __hfma2(R.b,  a0i, __hmul2(R.a, a0r))));
        ai2[k0] = __hfma2(R.nd, a1r, __hfma2(R.nc, a1i, __hfma2(R.nb, a0r, __hmul2(R.a, a0i))));
        ar2[k1] = __hfma2(R.nb, a1i, __hfma2(R.a,  a1r, __hfma2(R.d,  a0i, __hmul2(R.c, a0r))));
        ai2[k1] = __hfma2(R.b,  a1r, __hfma2(R.a,  a1i, __hfma2(R.nd, a0r, __hmul2(R.c, a0i))));
    }
}

// Gate on reg bit 0: pair lives inside one half2. Record fields are the
// mixed-pair constants cP,cQ,cR,cS,cQn,cSn.
__device__ __forceinline__ void reg_gate_lo(h2 ar2[32], h2 ai2[32], const GateRec& R) {
#pragma unroll
    for (int k = 0; k < 32; ++k) {
        const h2 arv = ar2[k], aiv = ai2[k];
        const h2 arx = __low2half2(arv), ary = __high2half2(arv);
        const h2 aix = __low2half2(aiv), aiy = __high2half2(aiv);
        ar2[k] = __hfma2(R.d,  aiy, __hfma2(R.c, ary, __hfma2(R.b,  aix, __hmul2(R.a, arx))));
        ai2[k] = __hfma2(R.nc, ary, __hfma2(R.c, aiy, __hfma2(R.nb, arx, __hmul2(R.a, aix))));
    }
}

// CNOT reg-part (lane-part deferred): value_new[r] = value_old[gray6(r)^32c],
// c = parity of OLD logical lane.
__device__ __forceinline__ void cnot_reg_part(h2 ar2[32], h2 ai2[32], int c) {
#pragma unroll
    for (int k = 0; k < 16; ++k) {
        const h2 a0 = ar2[k], a1 = ar2[k+16];
        ar2[k] = c ? a1 : a0;  ar2[k+16] = c ? a0 : a1;
        const h2 b0 = ai2[k], b1 = ai2[k+16];
        ai2[k] = c ? b1 : b0;  ai2[k+16] = c ? b0 : b1;
    }
    h2 nr[32], ni[32];
#pragma unroll
    for (int k = 0; k < 32; ++k) {
        const int g0 = (2*k)     ^ k;       // gray6(2k)
        const int g1 = (2*k + 1) ^ k;       // gray6(2k+1)
        nr[k] = __halves2half2(geth(ar2, g0), geth(ar2, g1));
        ni[k] = __halves2half2(geth(ai2, g0), geth(ai2, g1));
    }
#pragma unroll
    for (int k = 0; k < 32; ++k) { ar2[k] = nr[k]; ai2[k] = ni[k]; }
}

__global__ __launch_bounds__(64)
void qsim_kernel(const float* __restrict__ sb,        // (B,8) state_batch
                 const GateRec* __restrict__ recs,    // 96 gate records (d_ws)
                 const float* __restrict__ hw,        // (1,12) head_w
                 const float* __restrict__ hb,        // (1,) head_b
                 float* __restrict__ out) {           // (B,)
    const int lane   = threadIdx.x;                   // block = 1 wave
    const int sample = blockIdx.x;

    // ---- init to post-encoding state RX(x0)@w0, RY(x1)@w1 on |0..0>:
    // nonzero only at reg 0, lanes {0,16,32,48}.
    float c0, s0, c1, s1;
    __sincosf(0.5f * sb[sample*8 + 0], &s0, &c0);
    __sincosf(0.5f * sb[sample*8 + 1], &s1, &c1);
    h2 ar2[32], ai2[32];
    const h2 zero = __float2half2_rn(0.f);
#pragma unroll
    for (int k = 0; k < 32; ++k) { ar2[k] = zero; ai2[k] = zero; }
    {
        float a0 = 0.f, b0 = 0.f;
        if (lane == 0)  a0 =  c0*c1;
        if (lane == 16) a0 =  c0*s1;
        if (lane == 32) b0 = -s0*c1;
        if (lane == 48) b0 = -s0*s1;
        ar2[0] = __floats2half2_rn(a0, 0.f);
        ai2[0] = __floats2half2_rn(b0, 0.f);
    }

    int p = lane;                                  // logical lane = pi(lane)
    int Minv[6] = {1, 2, 4, 8, 16, 32};            // Minv[pb] = pi^-1(1<<pb)

#pragma unroll 1
    for (int l = 0; l < 8; ++l) {
        const GateRec* lr = recs + l*12;
        // wires 0..5 -> logical lane bits 5..0
#pragma unroll
        for (int w = 0; w < 6; ++w) {
            const GateRec R = lr[w];               // wave-uniform -> s_load
            const int pb = 5 - w;
            const bool b = (p >> pb) & 1;
            const h2 csi  = b ? R.b  : R.nb;
            const h2 ncsi = b ? R.nb : R.b;
            const h2 cor  = b ? R.c  : R.nc;
            lane_gate(ar2, ai2, (lane ^ Minv[pb]) << 2,
                      R.a, csi, ncsi, cor, /*coi=*/R.nd, /*ncoi=*/R.d);
        }
        // wires 6..11 -> reg bits 5..0
        { const GateRec R = lr[6];  reg_gate_hi<4>(ar2, ai2, R); }
        { const GateRec R = lr[7];  reg_gate_hi<3>(ar2, ai2, R); }
        { const GateRec R = lr[8];  reg_gate_hi<2>(ar2, ai2, R); }
        { const GateRec R = lr[9];  reg_gate_hi<1>(ar2, ai2, R); }
        { const GateRec R = lr[10]; reg_gate_hi<0>(ar2, ai2, R); }
        { const GateRec R = lr[11]; reg_gate_lo   (ar2, ai2, R); }
        if (l < 7) {
            const int c = __popc(p) & 1;           // parity of OLD logical lane
            cnot_reg_part(ar2, ai2, c);
            p = ginv6(p);                          // pi_new = Ginv o pi_old
#pragma unroll
            for (int pb = 5; pb >= 1; --pb) Minv[pb] ^= Minv[pb-1];
        }
    }

    // ---- epilogue (pre-last-CNOT state, prefix-parity sign masks, logical
    // lane = p):  wire w in 0..5: sign = parity(p >> (5-w));
    //             wire w in 6..11: sign = parity(p) * parity(r >> (11-w))
    float T = 0.f, S0=0.f,S1=0.f,S2=0.f,S3=0.f,S4=0.f,S5=0.f;
#pragma unroll
    for (int k = 0; k < 32; ++k) {
        const float2 rr = __half22float2(ar2[k]);
        const float2 ii = __half22float2(ai2[k]);
        const float px = rr.x*rr.x + ii.x*ii.x;
        const float py = rr.y*rr.y + ii.y*ii.y;
#pragma unroll
        for (int h = 0; h < 2; ++h) {
            const int r = 2*k + h;
            const float pv = h ? py : px;
            T  += pv;
            S0 += (__builtin_popcount(r >> 0) & 1) ? -pv : pv;
            S1 += (__builtin_popcount(r >> 1) & 1) ? -pv : pv;
            S2 += (__builtin_popcount(r >> 2) & 1) ? -pv : pv;
            S3 += (__builtin_popcount(r >> 3) & 1) ? -pv : pv;
            S4 += (__builtin_popcount(r >> 4) & 1) ? -pv : pv;
            S5 += (__builtin_popcount(r >> 5) & 1) ? -pv : pv;
        }
    }
    float WL = 0.f;
#pragma unroll
    for (int w = 0; w < 6; ++w) {
        const float hwv = hw[w];
        WL += (__popc(p >> (5 - w)) & 1) ? -hwv : hwv;
    }
    const float SR = hw[6]*S5 + hw[7]*S4 + hw[8]*S3
                   + hw[9]*S2 + hw[10]*S1 + hw[11]*S0;
    float u = T*WL + ((__popc(p) & 1) ? -SR : SR);
#pragma unroll
    for (int off = 1; off < 64; off <<= 1)
        u += bpermf((lane ^ off) << 2, u);
    if (lane == 0) out[sample] = u + hb[0];
}

extern "C" void kernel_launch(void* const* d_in, const int* in_sizes, int n_in,
                              void* d_out, int out_size, void* d_ws, size_t ws_size,
                              hipStream_t stream) {
    const float* sb  = (const float*)d_in[0];
    const float* wts = (const float*)d_in[1];
    const float* hw  = (const float*)d_in[2];
    const float* hb  = (const float*)d_in[3];
    float* out = (float*)d_out;
    GateRec* tbl = (GateRec*)d_ws;            // 96 * 32 B = 3 KB
    const int B = in_sizes[0] / 8;            // (B,8) state_batch
    coeff_kernel<<<1, 128, 0, stream>>>(wts, tbl);
    qsim_kernel<<<B, 64, 0, stream>>>(sb, tbl, hw, hb, out);
}

// Round 7
// 482.890 us; speedup vs baseline: 25.9465x; 1.0101x over previous
//
#include <hip/hip_runtime.h>
#include <hip/hip_fp16.h>

// ---------------------------------------------------------------------------
// Batched 12-qubit state-vector sim, one wave (64 lanes) per sample.
// State: 4096 complex amps = 64 complex/lane, FP16 __half2-packed: element
// r = 2k+h in half h of ar2[k]/ai2[k]. Every gate update is v_pk_fma_f16.
// Flat index y = (logical_lane<<6) | reg.  Wire w <-> flat bit p = 11-w.
//   wires 0..5  -> lane bits (cross-lane via ds_bpermute)
//   wires 6..11 -> reg bits (in-register)
// CNOT chain == new[d] = old[d ^ (d>>1)]. LANE part (linear gray map) is
// DEFERRED into (p, Minv[]) bookkeeping; REG part (gray6 relabel + ^32 on
// parity(p_old)) is physical. Last layer's CNOT elided via epilogue
// prefix-parity sign masks. Gate coefficients (batch-shared) precomputed by
// a 1-block pre-kernel into a 3KB table in d_ws (wave-uniform s_loads).
// ROUND 7: __launch_bounds__(64, 3). Rounds 4-6 reported VGPR_Count 64/56/52
// -- BELOW the 64 VGPRs the state alone needs -- with Occupancy ~38%
// (~3 waves/SIMD from ~150 TOTAL unified regs): the allocator was shadowing
// state into AGPRs (v_accvgpr_read/write on every access = the ~2x VALU
// excess over static inst count). min-3-waves/EU caps unified regs at ~170:
// comfortably fits state+temps (~110-150) in ARCH VGPRs, zero accvgpr moves,
// residency unchanged. NOT (64,4): cap 128 < need -> scratch spill
// (round-2 lesson: FETCH 373KB -> 14.7GB, 8.4x slower).
// Rot(phi,th,om) = [[(A,-B),(-C,-D)],[(C,-D),(A,B)]], A=ca*ch B=sa*ch
// C=cb*sh D=sb*sh.
// ---------------------------------------------------------------------------

typedef __half2 h2;

struct GateRec {            // 32 B, one per gate
    h2 a, b, c, d;          // splat(A),splat(B),splat(C),splat(D)   [w<11]
    h2 nb, nc, nd, pad;     // splat(-B),splat(-C),splat(-D)
};                          // w==11 (intra-half2): a..nc = cP,cQ,cR,cS,cQn,cSn

__device__ __forceinline__ h2 bperm2(int addr4, h2 v) {
    int x = __builtin_amdgcn_ds_bpermute(addr4, __builtin_bit_cast(int, v));
    return __builtin_bit_cast(h2, x);
}
__device__ __forceinline__ float bpermf(int addr4, float v) {
    return __int_as_float(__builtin_amdgcn_ds_bpermute(addr4, __float_as_int(v)));
}
__device__ __forceinline__ __half geth(const h2 a[32], int idx) {
    return (idx & 1) ? __high2half(a[idx >> 1]) : __low2half(a[idx >> 1]);
}
__device__ __forceinline__ int ginv6(int y) {
    return (y ^ (y >> 1) ^ (y >> 2) ^ (y >> 3) ^ (y >> 4) ^ (y >> 5)) & 63;
}
__device__ __forceinline__ h2 pack2f(float x, float y) {
    return __halves2half2(__float2half(x), __float2half(y));
}

// ---- pre-kernel: gate-coefficient table (96 gates, batch-shared) ----------
__global__ void coeff_kernel(const float* __restrict__ wts, GateRec* __restrict__ tbl) {
    const int g = threadIdx.x;
    if (g >= 96) return;
    const int l = g / 12, w = g % 12;
    const float* lw = wts + l*36 + w*3;
    const float phi = lw[0], th = lw[1], om = lw[2];
    float ch, sh, ca, sa, cb, sb;
    __sincosf(0.5f*th,       &sh, &ch);
    __sincosf(0.5f*(phi+om), &sa, &ca);
    __sincosf(0.5f*(phi-om), &sb, &cb);
    const float A = ca*ch, B = sa*ch, C = cb*sh, D = sb*sh;
    GateRec r;
    if (w == 11) {          // intra-half2 gate: mixed-pair constants
        r.a  = pack2f( A,  C);   // cP
        r.b  = pack2f( B,  D);   // cQ
        r.c  = pack2f(-C,  A);   // cR
        r.d  = pack2f( D, -B);   // cS
        r.nb = pack2f(-B, -D);   // cQn
        r.nc = pack2f(-D,  B);   // cSn
        r.nd = pack2f(0.f, 0.f); r.pad = pack2f(0.f, 0.f);
    } else {
        r.a  = pack2f( A,  A); r.b  = pack2f( B,  B);
        r.c  = pack2f( C,  C); r.d  = pack2f( D,  D);
        r.nb = pack2f(-B, -B); r.nc = pack2f(-C, -C);
        r.nd = pack2f(-D, -D); r.pad = pack2f(0.f, 0.f);
    }
    tbl[g] = r;
}

// Gate on a (logical) lane bit. out = cs*x + co*partner; partner fetched from
// physical lane (lane ^ Minv). Coefficients pre-selected h2 (from SGPR recs).
__device__ __forceinline__ void lane_gate(h2 ar2[32], h2 ai2[32], int addr4,
                                          h2 csr, h2 csi, h2 ncsi,
                                          h2 cor, h2 coi, h2 ncoi) {
    constexpr int CH = 4;
    h2 tr[CH], ti[CH], pr[CH], pi[CH];
#pragma unroll
    for (int k = 0; k < CH; ++k) {
        tr[k] = bperm2(addr4, ar2[k]);
        ti[k] = bperm2(addr4, ai2[k]);
    }
#pragma unroll
    for (int base = 0; base < 32; base += CH) {
        if (base + CH < 32) {
#pragma unroll
            for (int k = 0; k < CH; ++k) {
                pr[k] = bperm2(addr4, ar2[base+CH+k]);
                pi[k] = bperm2(addr4, ai2[base+CH+k]);
            }
        }
#pragma unroll
        for (int k = 0; k < CH; ++k) {
            const int r = base + k;
            const h2 xr = ar2[r], xi = ai2[r];
            // ar = csr*xr - csi*xi + cor*tr - coi*ti
            ar2[r] = __hfma2(ncoi, ti[k], __hfma2(cor, tr[k], __hfma2(ncsi, xi, __hmul2(csr, xr))));
            // ai = csr*xi + csi*xr + cor*ti + coi*tr
            ai2[r] = __hfma2( coi, tr[k], __hfma2(cor, ti[k], __hfma2( csi, xr, __hmul2(csr, xi))));
        }
#pragma unroll
        for (int k = 0; k < CH; ++k) { tr[k] = pr[k]; ti[k] = pi[k]; }
    }
}

// Gate on reg bit P>=1 (half2-index bit P2=P-1): pairs of whole half2s.
template<int P2>
__device__ __forceinline__ void reg_gate_hi(h2 ar2[32], h2 ai2[32], const GateRec& R) {
#pragma unroll
    for (int k0 = 0; k0 < 32; ++k0) {
        if (k0 & (1 << P2)) continue;          // compile-time filtered
        const int k1 = k0 | (1 << P2);
        const h2 a0r = ar2[k0], a0i = ai2[k0], a1r = ar2[k1], a1i = ai2[k1];
        ar2[k0] = __hfma2(R.d,  a1i, __hfma2(R.nc, a1r, __hfma2(R.b,  a0i, __hmul2(R.a, a0r))));
        ai2[k0] = __hfma2(R.nd, a1r, __hfma2(R.nc, a1i, __hfma2(R.nb, a0r, __hmul2(R.a, a0i))));
        ar2[k1] = __hfma2(R.nb, a1i, __hfma2(R.a,  a1r, __hfma2(R.d,  a0i, __hmul2(R.c, a0r))));
        ai2[k1] = __hfma2(R.b,  a1r, __hfma2(R.a,  a1i, __hfma2(R.nd, a0r, __hmul2(R.c, a0i))));
    }
}

// Gate on reg bit 0: pair lives inside one half2. Record fields are the
// mixed-pair constants cP,cQ,cR,cS,cQn,cSn.
__device__ __forceinline__ void reg_gate_lo(h2 ar2[32], h2 ai2[32], const GateRec& R) {
#pragma unroll
    for (int k = 0; k < 32; ++k) {
        const h2 arv = ar2[k], aiv = ai2[k];
        const h2 arx = __low2half2(arv), ary = __high2half2(arv);
        const h2 aix = __low2half2(aiv), aiy = __high2half2(aiv);
        ar2[k] = __hfma2(R.d,  aiy, __hfma2(R.c, ary, __hfma2(R.b,  aix, __hmul2(R.a, arx))));
        ai2[k] = __hfma2(R.nc, ary, __hfma2(R.c, aiy, __hfma2(R.nb, arx, __hmul2(R.a, aix))));
    }
}

// CNOT reg-part (lane-part deferred): value_new[r] = value_old[gray6(r)^32c],
// c = parity of OLD logical lane.
__device__ __forceinline__ void cnot_reg_part(h2 ar2[32], h2 ai2[32], int c) {
#pragma unroll
    for (int k = 0; k < 16; ++k) {
        const h2 a0 = ar2[k], a1 = ar2[k+16];
        ar2[k] = c ? a1 : a0;  ar2[k+16] = c ? a0 : a1;
        const h2 b0 = ai2[k], b1 = ai2[k+16];
        ai2[k] = c ? b1 : b0;  ai2[k+16] = c ? b0 : b1;
    }
    h2 nr[32], ni[32];
#pragma unroll
    for (int k = 0; k < 32; ++k) {
        const int g0 = (2*k)     ^ k;       // gray6(2k)
        const int g1 = (2*k + 1) ^ k;       // gray6(2k+1)
        nr[k] = __halves2half2(geth(ar2, g0), geth(ar2, g1));
        ni[k] = __halves2half2(geth(ai2, g0), geth(ai2, g1));
    }
#pragma unroll
    for (int k = 0; k < 32; ++k) { ar2[k] = nr[k]; ai2[k] = ni[k]; }
}

__global__ __launch_bounds__(64, 3)
void qsim_kernel(const float* __restrict__ sb,        // (B,8) state_batch
                 const GateRec* __restrict__ recs,    // 96 gate records (d_ws)
                 const float* __restrict__ hw,        // (1,12) head_w
                 const float* __restrict__ hb,        // (1,) head_b
                 float* __restrict__ out) {           // (B,)
    const int lane   = threadIdx.x;                   // block = 1 wave
    const int sample = blockIdx.x;

    // ---- init to post-encoding state RX(x0)@w0, RY(x1)@w1 on |0..0>:
    // nonzero only at reg 0, lanes {0,16,32,48}.
    float c0, s0, c1, s1;
    __sincosf(0.5f * sb[sample*8 + 0], &s0, &c0);
    __sincosf(0.5f * sb[sample*8 + 1], &s1, &c1);
    h2 ar2[32], ai2[32];
    const h2 zero = __float2half2_rn(0.f);
#pragma unroll
    for (int k = 0; k < 32; ++k) { ar2[k] = zero; ai2[k] = zero; }
    {
        float a0 = 0.f, b0 = 0.f;
        if (lane == 0)  a0 =  c0*c1;
        if (lane == 16) a0 =  c0*s1;
        if (lane == 32) b0 = -s0*c1;
        if (lane == 48) b0 = -s0*s1;
        ar2[0] = __floats2half2_rn(a0, 0.f);
        ai2[0] = __floats2half2_rn(b0, 0.f);
    }

    int p = lane;                                  // logical lane = pi(lane)
    int Minv[6] = {1, 2, 4, 8, 16, 32};            // Minv[pb] = pi^-1(1<<pb)

#pragma unroll 1
    for (int l = 0; l < 8; ++l) {
        const GateRec* lr = recs + l*12;
        // wires 0..5 -> logical lane bits 5..0
#pragma unroll
        for (int w = 0; w < 6; ++w) {
            const GateRec R = lr[w];               // wave-uniform -> s_load
            const int pb = 5 - w;
            const bool b = (p >> pb) & 1;
            const h2 csi  = b ? R.b  : R.nb;
            const h2 ncsi = b ? R.nb : R.b;
            const h2 cor  = b ? R.c  : R.nc;
            lane_gate(ar2, ai2, (lane ^ Minv[pb]) << 2,
                      R.a, csi, ncsi, cor, /*coi=*/R.nd, /*ncoi=*/R.d);
        }
        // wires 6..11 -> reg bits 5..0
        { const GateRec R = lr[6];  reg_gate_hi<4>(ar2, ai2, R); }
        { const GateRec R = lr[7];  reg_gate_hi<3>(ar2, ai2, R); }
        { const GateRec R = lr[8];  reg_gate_hi<2>(ar2, ai2, R); }
        { const GateRec R = lr[9];  reg_gate_hi<1>(ar2, ai2, R); }
        { const GateRec R = lr[10]; reg_gate_hi<0>(ar2, ai2, R); }
        { const GateRec R = lr[11]; reg_gate_lo   (ar2, ai2, R); }
        if (l < 7) {
            const int c = __popc(p) & 1;           // parity of OLD logical lane
            cnot_reg_part(ar2, ai2, c);
            p = ginv6(p);                          // pi_new = Ginv o pi_old
#pragma unroll
            for (int pb = 5; pb >= 1; --pb) Minv[pb] ^= Minv[pb-1];
        }
    }

    // ---- epilogue (pre-last-CNOT state, prefix-parity sign masks, logical
    // lane = p):  wire w in 0..5: sign = parity(p >> (5-w));
    //             wire w in 6..11: sign = parity(p) * parity(r >> (11-w))
    float T = 0.f, S0=0.f,S1=0.f,S2=0.f,S3=0.f,S4=0.f,S5=0.f;
#pragma unroll
    for (int k = 0; k < 32; ++k) {
        const float2 rr = __half22float2(ar2[k]);
        const float2 ii = __half22float2(ai2[k]);
        const float px = rr.x*rr.x + ii.x*ii.x;
        const float py = rr.y*rr.y + ii.y*ii.y;
#pragma unroll
        for (int h = 0; h < 2; ++h) {
            const int r = 2*k + h;
            const float pv = h ? py : px;
            T  += pv;
            S0 += (__builtin_popcount(r >> 0) & 1) ? -pv : pv;
            S1 += (__builtin_popcount(r >> 1) & 1) ? -pv : pv;
            S2 += (__builtin_popcount(r >> 2) & 1) ? -pv : pv;
            S3 += (__builtin_popcount(r >> 3) & 1) ? -pv : pv;
            S4 += (__builtin_popcount(r >> 4) & 1) ? -pv : pv;
            S5 += (__builtin_popcount(r >> 5) & 1) ? -pv : pv;
        }
    }
    float WL = 0.f;
#pragma unroll
    for (int w = 0; w < 6; ++w) {
        const float hwv = hw[w];
        WL += (__popc(p >> (5 - w)) & 1) ? -hwv : hwv;
    }
    const float SR = hw[6]*S5 + hw[7]*S4 + hw[8]*S3
                   + hw[9]*S2 + hw[10]*S1 + hw[11]*S0;
    float u = T*WL + ((__popc(p) & 1) ? -SR : SR);
#pragma unroll
    for (int off = 1; off < 64; off <<= 1)
        u += bpermf((lane ^ off) << 2, u);
    if (lane == 0) out[sample] = u + hb[0];
}

extern "C" void kernel_launch(void* const* d_in, const int* in_sizes, int n_in,
                              void* d_out, int out_size, void* d_ws, size_t ws_size,
                              hipStream_t stream) {
    const float* sb  = (const float*)d_in[0];
    const float* wts = (const float*)d_in[1];
    const float* hw  = (const float*)d_in[2];
    const float* hb  = (const float*)d_in[3];
    float* out = (float*)d_out;
    GateRec* tbl = (GateRec*)d_ws;            // 96 * 32 B = 3 KB
    const int B = in_sizes[0] / 8;            // (B,8) state_batch
    coeff_kernel<<<1, 128, 0, stream>>>(wts, tbl);
    qsim_kernel<<<B, 64, 0, stream>>>(sb, tbl, hw, hb, out);
}